// Round 1
// baseline (4610.086 us; speedup 1.0000x reference)
//
#include <hip/hip_runtime.h>
#include <math.h>

// Problem constants (from reference)
constexpr int NN = 100000;          // nodes
constexpr int EE = 6400000;         // edges
constexpr int FF = 6;               // features
constexpr int RG = 500;             // reg head hidden
constexpr double MM = 600000.0;     // N*F elements for global norm

constexpr int NODE_BLOCK = 256;
constexpr int NODE_GRID  = (NN + NODE_BLOCK - 1) / NODE_BLOCK;
constexpr int EDGE_BLOCK = 256;
constexpr int EDGE_GRID  = (EE + EDGE_BLOCK - 1) / EDGE_BLOCK;

__device__ __forceinline__ float leakyf(float v, float s) { return v >= 0.f ? v : s * v; }

// mean / inv-std from accumulated sum, sumsq (unbiased std, ddof=1)
__device__ __forceinline__ void norm_params(const double* __restrict__ S, float& mu, float& istd) {
    double s1 = S[0], s2 = S[1];
    double mean = s1 / MM;
    double var  = (s2 - s1 * mean) / (MM - 1.0);
    mu   = (float)mean;
    istd = (float)(1.0 / sqrt(var));
}

// wave(64)-level reduce of two doubles, one f64 atomic pair per wave
__device__ __forceinline__ void reduce2_add(double s1, double s2, double* __restrict__ d) {
    #pragma unroll
    for (int off = 32; off > 0; off >>= 1) {
        s1 += __shfl_down(s1, off, 64);
        s2 += __shfl_down(s2, off, 64);
    }
    if ((threadIdx.x & 63) == 0) {
        atomicAdd(&d[0], s1);
        atomicAdd(&d[1], s2);
    }
}

// K0: collapse regression head (Wresh@W1, bresh@W1+b1, same for W2); zero norm scalars.
__global__ void head_prep(const float* __restrict__ Wresh, const float* __restrict__ bresh,
                          const float* __restrict__ W1, const float* __restrict__ b1,
                          const float* __restrict__ W2, const float* __restrict__ b2,
                          float* __restrict__ head, double* __restrict__ S) {
    int t = threadIdx.x;
    if (t < 8) S[t] = 0.0;
    if (t < FF) {
        float a1 = 0.f, a2 = 0.f;
        for (int g = 0; g < RG; ++g) {
            float w = Wresh[t * RG + g];
            a1 = fmaf(w, W1[g], a1);
            a2 = fmaf(w, W2[g], a2);
        }
        head[t]     = a1;   // cW1[f]
        head[8 + t] = a2;   // cW2[f]
    } else if (t == FF) {
        float a1 = 0.f, a2 = 0.f;
        for (int g = 0; g < RG; ++g) {
            a1 = fmaf(bresh[g], W1[g], a1);
            a2 = fmaf(bresh[g], W2[g], a2);
        }
        head[6]  = a1 + b1[0];  // c1
        head[14] = a2 + b2[0];  // c2
    }
}

// K1: (optionally normalize input) -> xl = x@Wl+bl, xr = x@Wr+br (padded stride 8);
//     zero per-node accumulators.
template <int LAYER>
__global__ __launch_bounds__(NODE_BLOCK)
void node_transform(const float* __restrict__ xin, const double* __restrict__ Snorm,
                    const float* __restrict__ Wl, const float* __restrict__ bl,
                    const float* __restrict__ Wr, const float* __restrict__ br,
                    float* __restrict__ xl, float* __restrict__ xr,
                    float* __restrict__ x2out,
                    float* __restrict__ num, float* __restrict__ denomv) {
    int n = blockIdx.x * blockDim.x + threadIdx.x;
    if (n >= NN) return;
    float v[FF];
    if (LAYER == 0) {
        #pragma unroll
        for (int f = 0; f < FF; ++f) v[f] = xin[n * FF + f];
    } else {
        float mu, istd;
        norm_params(Snorm, mu, istd);
        #pragma unroll
        for (int f = 0; f < FF; ++f) {
            v[f] = (xin[n * FF + f] - mu) * istd;
            x2out[n * FF + f] = v[f];      // x2 needed by later residuals
        }
    }
    float ol[FF], orr[FF];
    #pragma unroll
    for (int j = 0; j < FF; ++j) { ol[j] = bl[j]; orr[j] = br[j]; }
    #pragma unroll
    for (int k = 0; k < FF; ++k) {
        float vk = v[k];
        #pragma unroll
        for (int j = 0; j < FF; ++j) {
            ol[j]  = fmaf(vk, Wl[k * FF + j], ol[j]);
            orr[j] = fmaf(vk, Wr[k * FF + j], orr[j]);
        }
    }
    float4* xl4 = reinterpret_cast<float4*>(xl + n * 8);
    float4* xr4 = reinterpret_cast<float4*>(xr + n * 8);
    xl4[0] = make_float4(ol[0], ol[1], ol[2], ol[3]);
    xl4[1] = make_float4(ol[4], ol[5], 0.f, 0.f);
    xr4[0] = make_float4(orr[0], orr[1], orr[2], orr[3]);
    xr4[1] = make_float4(orr[4], orr[5], 0.f, 0.f);
    float4* nm4 = reinterpret_cast<float4*>(num + n * 8);
    nm4[0] = make_float4(0.f, 0.f, 0.f, 0.f);
    nm4[1] = make_float4(0.f, 0.f, 0.f, 0.f);
    denomv[n] = 0.f;
}

// K2: fused edge pass. logit -> w=exp(logit) (no segment-max needed: logits bounded ~6)
//     -> atomic denom[dst] += w ; num[dst][f] += w * xl[src][f]
__global__ __launch_bounds__(EDGE_BLOCK)
void edge_pass(const int* __restrict__ ei, const float* __restrict__ eattr,
               const float* __restrict__ xl, const float* __restrict__ xr,
               const float* __restrict__ Wef, const float* __restrict__ attf,
               float* __restrict__ num, float* __restrict__ denomv) {
    float we0[FF], we1[FF], at[FF];
    #pragma unroll
    for (int f = 0; f < FF; ++f) { we0[f] = Wef[f]; we1[f] = Wef[FF + f]; at[f] = attf[f]; }

    int idx = blockIdx.x * blockDim.x + threadIdx.x;
    if (idx >= EE) return;

    int s = ei[idx] % NN;
    int d = ei[EE + idx] % NN;
    float2 ea = reinterpret_cast<const float2*>(eattr)[idx];

    const float4* xls = reinterpret_cast<const float4*>(xl + (size_t)s * 8);
    float4 a0 = xls[0], a1 = xls[1];
    const float4* xrd = reinterpret_cast<const float4*>(xr + (size_t)d * 8);
    float4 b0 = xrd[0], b1 = xrd[1];

    float av[FF] = {a0.x, a0.y, a0.z, a0.w, a1.x, a1.y};
    float bv[FF] = {b0.x, b0.y, b0.z, b0.w, b1.x, b1.y};

    float logit = 0.f;
    #pragma unroll
    for (int f = 0; f < FF; ++f) {
        float m = av[f] + bv[f] + fmaf(ea.y, we1[f], ea.x * we0[f]);
        m = m >= 0.f ? m : 0.2f * m;
        logit = fmaf(at[f], m, logit);
    }
    float w = __expf(logit);

    unsafeAtomicAdd(&denomv[d], w);
    float* nd = num + (size_t)d * 8;
    #pragma unroll
    for (int f = 0; f < FF; ++f) unsafeAtomicAdd(&nd[f], w * av[f]);
}

// K3: h = leaky(num/denom + bias_g, 0.01) + residuals; accumulate sums for norm_global(h)
template <int LAYER>
__global__ __launch_bounds__(NODE_BLOCK)
void node_finalize(const float* __restrict__ num, const float* __restrict__ denomv,
                   const float* __restrict__ biasg,
                   const float* __restrict__ x0, const float* __restrict__ x1n0,
                   const float* __restrict__ x2,
                   float* __restrict__ h, double* __restrict__ Sout) {
    int n = blockIdx.x * blockDim.x + threadIdx.x;
    double s1 = 0.0, s2 = 0.0;
    if (n < NN) {
        float dn  = denomv[n];
        float inv = dn != 0.f ? 1.f / dn : 0.f;
        #pragma unroll
        for (int f = 0; f < FF; ++f) {
            float t = leakyf(num[n * 8 + f] * inv + biasg[f], 0.01f);
            t += x0[n * FF + f];
            if (LAYER == 1) t += x1n0[n * FF + f] + x2[n * FF + f];
            h[n * FF + f] = t;
            s1 += t;
            s2 += (double)t * (double)t;
        }
    }
    reduce2_add(s1, s2, Sout);
}

// K4: x1n = norm(h); h2 = leaky(x1n@ff1W+ff1b)@ff2W+ff2b + residuals.
//     LAYER 0: store x1n, h2; accumulate sums for norm_global(h2).
//     LAYER 1: apply collapsed head -> d_out[N,2].
template <int LAYER>
__global__ __launch_bounds__(NODE_BLOCK)
void node_ffn(const float* __restrict__ h, const double* __restrict__ Snorm,
              const float* __restrict__ f1W, const float* __restrict__ f1b,
              const float* __restrict__ f2W, const float* __restrict__ f2b,
              const float* __restrict__ x0, const float* __restrict__ x1n0_in,
              const float* __restrict__ x2,
              float* __restrict__ x1n0_out, float* __restrict__ gout,
              double* __restrict__ Sgout,
              const float* __restrict__ head, float* __restrict__ dout) {
    int n = blockIdx.x * blockDim.x + threadIdx.x;
    double s1 = 0.0, s2 = 0.0;
    if (n < NN) {
        float mu, istd;
        norm_params(Snorm, mu, istd);
        float xn[FF];
        #pragma unroll
        for (int f = 0; f < FF; ++f) xn[f] = (h[n * FF + f] - mu) * istd;

        float u[FF], w[FF];
        #pragma unroll
        for (int j = 0; j < FF; ++j) u[j] = f1b[j];
        #pragma unroll
        for (int k = 0; k < FF; ++k) {
            float vk = xn[k];
            #pragma unroll
            for (int j = 0; j < FF; ++j) u[j] = fmaf(vk, f1W[k * FF + j], u[j]);
        }
        #pragma unroll
        for (int j = 0; j < FF; ++j) u[j] = leakyf(u[j], 0.01f);
        #pragma unroll
        for (int j = 0; j < FF; ++j) w[j] = f2b[j];
        #pragma unroll
        for (int k = 0; k < FF; ++k) {
            float vk = u[k];
            #pragma unroll
            for (int j = 0; j < FF; ++j) w[j] = fmaf(vk, f2W[k * FF + j], w[j]);
        }
        #pragma unroll
        for (int f = 0; f < FF; ++f) {
            w[f] += xn[f] + x0[n * FF + f];
            if (LAYER == 1) w[f] += x2[n * FF + f] + x1n0_in[n * FF + f];
        }
        if (LAYER == 0) {
            #pragma unroll
            for (int f = 0; f < FF; ++f) {
                x1n0_out[n * FF + f] = xn[f];
                gout[n * FF + f]     = w[f];
                s1 += w[f];
                s2 += (double)w[f] * (double)w[f];
            }
        } else {
            float o1 = head[6], o2 = head[14];
            #pragma unroll
            for (int f = 0; f < FF; ++f) {
                o1 = fmaf(w[f], head[f], o1);
                o2 = fmaf(w[f], head[8 + f], o2);
            }
            dout[n * 2 + 0] = o1;
            dout[n * 2 + 1] = o2;
        }
    }
    if (LAYER == 0) reduce2_add(s1, s2, Sgout);
}

extern "C" void kernel_launch(void* const* d_in, const int* in_sizes, int n_in,
                              void* d_out, int out_size, void* d_ws, size_t ws_size,
                              hipStream_t stream) {
    const float* x     = (const float*)d_in[0];
    const float* eattr = (const float*)d_in[1];
    const float* Wl    = (const float*)d_in[2];
    const float* bl    = (const float*)d_in[3];
    const float* Wr    = (const float*)d_in[4];
    const float* br    = (const float*)d_in[5];
    const float* We    = (const float*)d_in[6];
    const float* att   = (const float*)d_in[7];
    const float* biasg = (const float*)d_in[8];
    const float* ff1W  = (const float*)d_in[9];
    const float* ff1b  = (const float*)d_in[10];
    const float* ff2W  = (const float*)d_in[11];
    const float* ff2b  = (const float*)d_in[12];
    const float* Wresh = (const float*)d_in[13];
    const float* bresh = (const float*)d_in[14];
    const float* W1    = (const float*)d_in[15];
    const float* b1    = (const float*)d_in[16];
    const float* W2    = (const float*)d_in[17];
    const float* b2    = (const float*)d_in[18];
    const int*   ei    = (const int*)d_in[19];
    float* out = (float*)d_out;

    // workspace layout
    double* S    = (double*)d_ws;              // 8 doubles: [0,1]=h L0, [2,3]=h2 L0, [4,5]=h L1
    float*  head = (float*)d_ws + 16;          // 16 floats: cW1[6],c1,_,cW2[6],c2,_
    float*  xl   = (float*)d_ws + 32;          // N*8
    float*  xr   = xl + NN * 8;                // N*8
    float*  num  = xr + NN * 8;                // N*8
    float*  dnm  = num + NN * 8;               // N
    float*  h    = dnm + NN;                   // N*6 (reused both layers)
    float*  x1n0 = h + NN * FF;                // N*6 (x1 == x3 for layer 1)
    float*  x2   = x1n0 + NN * FF;             // N*6 (normalized h2_0)
    float*  g    = x2 + NN * FF;               // N*6 (h2_0 pre-norm)

    head_prep<<<1, 64, 0, stream>>>(Wresh, bresh, W1, b1, W2, b2, head, S);

    // ---- layer 0 ----
    node_transform<0><<<NODE_GRID, NODE_BLOCK, 0, stream>>>(
        x, nullptr, Wl, bl, Wr, br, xl, xr, nullptr, num, dnm);
    edge_pass<<<EDGE_GRID, EDGE_BLOCK, 0, stream>>>(
        ei, eattr, xl, xr, We, att, num, dnm);
    node_finalize<0><<<NODE_GRID, NODE_BLOCK, 0, stream>>>(
        num, dnm, biasg, x, nullptr, nullptr, h, S + 0);
    node_ffn<0><<<NODE_GRID, NODE_BLOCK, 0, stream>>>(
        h, S + 0, ff1W, ff1b, ff2W, ff2b, x, nullptr, nullptr,
        x1n0, g, S + 2, nullptr, nullptr);

    // ---- layer 1 ----
    node_transform<1><<<NODE_GRID, NODE_BLOCK, 0, stream>>>(
        g, S + 2, Wl + 36, bl + 6, Wr + 36, br + 6, xl, xr, x2, num, dnm);
    edge_pass<<<EDGE_GRID, EDGE_BLOCK, 0, stream>>>(
        ei, eattr, xl, xr, We + 12, att + 6, num, dnm);
    node_finalize<1><<<NODE_GRID, NODE_BLOCK, 0, stream>>>(
        num, dnm, biasg + 6, x, x1n0, x2, h, S + 4);
    node_ffn<1><<<NODE_GRID, NODE_BLOCK, 0, stream>>>(
        h, S + 4, ff1W + 36, ff1b + 6, ff2W + 36, ff2b + 6, x, x1n0, x2,
        nullptr, nullptr, nullptr, head, out);
}

// Round 2
// 1915.360 us; speedup vs baseline: 2.4069x; 2.4069x over previous
//
#include <hip/hip_runtime.h>
#include <math.h>

// Problem constants (from reference)
constexpr int NN = 100000;          // nodes
constexpr int EE = 6400000;         // edges
constexpr int FF = 6;               // features
constexpr int RG = 500;             // reg head hidden
constexpr double MM = 600000.0;     // N*F elements for global norm

constexpr int NODE_BLOCK = 256;
constexpr int NODE_GRID  = (NN + NODE_BLOCK - 1) / NODE_BLOCK;
constexpr int EDGE_BLOCK = 256;
constexpr int EDGE_GRID  = (EE + EDGE_BLOCK - 1) / EDGE_BLOCK;

__device__ __forceinline__ float leakyf(float v, float s) { return v >= 0.f ? v : s * v; }

__device__ __forceinline__ void norm_params(const double* __restrict__ S, float& mu, float& istd) {
    double s1 = S[0], s2 = S[1];
    double mean = s1 / MM;
    double var  = (s2 - s1 * mean) / (MM - 1.0);
    mu   = (float)mean;
    istd = (float)(1.0 / sqrt(var));
}

__device__ __forceinline__ void reduce2_add(double s1, double s2, double* __restrict__ d) {
    #pragma unroll
    for (int off = 32; off > 0; off >>= 1) {
        s1 += __shfl_down(s1, off, 64);
        s2 += __shfl_down(s2, off, 64);
    }
    if ((threadIdx.x & 63) == 0) {
        atomicAdd(&d[0], s1);
        atomicAdd(&d[1], s2);
    }
}

// K0: collapse regression head; zero norm scalars.
__global__ void head_prep(const float* __restrict__ Wresh, const float* __restrict__ bresh,
                          const float* __restrict__ W1, const float* __restrict__ b1,
                          const float* __restrict__ W2, const float* __restrict__ b2,
                          float* __restrict__ head, double* __restrict__ S) {
    int t = threadIdx.x;
    if (t < 8) S[t] = 0.0;
    if (t < FF) {
        float a1 = 0.f, a2 = 0.f;
        for (int g = 0; g < RG; ++g) {
            float w = Wresh[t * RG + g];
            a1 = fmaf(w, W1[g], a1);
            a2 = fmaf(w, W2[g], a2);
        }
        head[t]     = a1;
        head[8 + t] = a2;
    } else if (t == FF) {
        float a1 = 0.f, a2 = 0.f;
        for (int g = 0; g < RG; ++g) {
            a1 = fmaf(bresh[g], W1[g], a1);
            a2 = fmaf(bresh[g], W2[g], a2);
        }
        head[6]  = a1 + b1[0];
        head[14] = a2 + b2[0];
    }
}

// ---------- CSR build ----------

__global__ __launch_bounds__(256) void zero_counts(unsigned* __restrict__ counts) {
    int i = blockIdx.x * blockDim.x + threadIdx.x;
    if (i < NN) counts[i] = 0u;
}

__global__ __launch_bounds__(EDGE_BLOCK)
void count_edges(const int* __restrict__ ei, unsigned* __restrict__ counts,
                 unsigned* __restrict__ rank) {
    int e = blockIdx.x * blockDim.x + threadIdx.x;
    if (e >= EE) return;
    int d = ei[EE + e] % NN;
    rank[e] = atomicAdd(&counts[d], 1u);
}

// single-block 2-level exclusive scan of counts[NN] -> offsets[NN+1]
__global__ __launch_bounds__(1024)
void scan_counts(const unsigned* __restrict__ counts, int* __restrict__ offsets) {
    __shared__ unsigned ls[1024];
    const int CH = 98;                       // 1024*98 >= 100000
    int t = threadIdx.x;
    int beg = t * CH, fin = min(beg + CH, NN);
    unsigned p = 0;
    for (int i = beg; i < fin; ++i) p += counts[i];
    ls[t] = p;
    __syncthreads();
    for (int o = 1; o < 1024; o <<= 1) {
        unsigned add = (t >= o) ? ls[t - o] : 0u;
        __syncthreads();
        ls[t] += add;
        __syncthreads();
    }
    unsigned run = (t > 0) ? ls[t - 1] : 0u;  // exclusive base
    for (int i = beg; i < fin; ++i) { offsets[i] = (int)run; run += counts[i]; }
    if (t == 1023) offsets[NN] = (int)ls[1023];
}

__global__ __launch_bounds__(EDGE_BLOCK)
void scatter_edges(const int* __restrict__ ei, const unsigned* __restrict__ rank,
                   const float* __restrict__ eattr, const int* __restrict__ offsets,
                   int* __restrict__ src_sorted, float* __restrict__ ea_sorted) {
    int e = blockIdx.x * blockDim.x + threadIdx.x;
    if (e >= EE) return;
    int s = ei[e] % NN;
    int d = ei[EE + e] % NN;
    int pos = offsets[d] + (int)rank[e];
    src_sorted[pos] = s;
    reinterpret_cast<float2*>(ea_sorted)[pos] = reinterpret_cast<const float2*>(eattr)[e];
}

// ---------- node transform (xl = x@Wl+bl, xr = x@Wr+br; padded stride 8) ----------
template <int LAYER>
__global__ __launch_bounds__(NODE_BLOCK)
void node_transform(const float* __restrict__ xin, const double* __restrict__ Snorm,
                    const float* __restrict__ Wl, const float* __restrict__ bl,
                    const float* __restrict__ Wr, const float* __restrict__ br,
                    float* __restrict__ xl, float* __restrict__ xr,
                    float* __restrict__ x2out) {
    int n = blockIdx.x * blockDim.x + threadIdx.x;
    if (n >= NN) return;
    float v[FF];
    if (LAYER == 0) {
        #pragma unroll
        for (int f = 0; f < FF; ++f) v[f] = xin[n * FF + f];
    } else {
        float mu, istd;
        norm_params(Snorm, mu, istd);
        #pragma unroll
        for (int f = 0; f < FF; ++f) {
            v[f] = (xin[n * FF + f] - mu) * istd;
            x2out[n * FF + f] = v[f];
        }
    }
    float ol[FF], orr[FF];
    #pragma unroll
    for (int j = 0; j < FF; ++j) { ol[j] = bl[j]; orr[j] = br[j]; }
    #pragma unroll
    for (int k = 0; k < FF; ++k) {
        float vk = v[k];
        #pragma unroll
        for (int j = 0; j < FF; ++j) {
            ol[j]  = fmaf(vk, Wl[k * FF + j], ol[j]);
            orr[j] = fmaf(vk, Wr[k * FF + j], orr[j]);
        }
    }
    float4* xl4 = reinterpret_cast<float4*>(xl + n * 8);
    float4* xr4 = reinterpret_cast<float4*>(xr + n * 8);
    xl4[0] = make_float4(ol[0], ol[1], ol[2], ol[3]);
    xl4[1] = make_float4(ol[4], ol[5], 0.f, 0.f);
    xr4[0] = make_float4(orr[0], orr[1], orr[2], orr[3]);
    xr4[1] = make_float4(orr[4], orr[5], 0.f, 0.f);
}

// ---------- fused CSR gather + softmax + aggregate + finalize ----------
// one wave per destination node; no atomics (except 2 f64/block for norm sums)
template <int LAYER>
__global__ __launch_bounds__(256)
void gat_gather(const int* __restrict__ offsets, const int* __restrict__ src_sorted,
                const float* __restrict__ ea_sorted,
                const float* __restrict__ xl, const float* __restrict__ xr,
                const float* __restrict__ Wef, const float* __restrict__ attf,
                const float* __restrict__ biasg,
                const float* __restrict__ x0, const float* __restrict__ x1n0,
                const float* __restrict__ x2,
                float* __restrict__ h, double* __restrict__ Sout) {
    __shared__ double sh[8];
    int wid  = threadIdx.x >> 6;
    int lane = threadIdx.x & 63;
    int n = blockIdx.x * 4 + wid;
    double s1 = 0.0, s2 = 0.0;
    if (n < NN) {
        float we0[FF], we1[FF], at[FF];
        #pragma unroll
        for (int f = 0; f < FF; ++f) { we0[f] = Wef[f]; we1[f] = Wef[FF + f]; at[f] = attf[f]; }
        const float4* xrd = reinterpret_cast<const float4*>(xr + (size_t)n * 8);
        float4 b0 = xrd[0], b1 = xrd[1];
        float bv[FF] = {b0.x, b0.y, b0.z, b0.w, b1.x, b1.y};

        int off = offsets[n], end = offsets[n + 1];
        float dsum = 0.f, nsum[FF] = {0.f, 0.f, 0.f, 0.f, 0.f, 0.f};
        for (int k = off + lane; k < end; k += 64) {
            int s = src_sorted[k];
            float2 ea = reinterpret_cast<const float2*>(ea_sorted)[k];
            const float4* xls = reinterpret_cast<const float4*>(xl + (size_t)s * 8);
            float4 a0 = xls[0], a1 = xls[1];
            float av[FF] = {a0.x, a0.y, a0.z, a0.w, a1.x, a1.y};
            float logit = 0.f;
            #pragma unroll
            for (int f = 0; f < FF; ++f) {
                float m = av[f] + bv[f] + fmaf(ea.y, we1[f], ea.x * we0[f]);
                m = m >= 0.f ? m : 0.2f * m;
                logit = fmaf(at[f], m, logit);
            }
            float w = __expf(logit);
            dsum += w;
            #pragma unroll
            for (int f = 0; f < FF; ++f) nsum[f] = fmaf(w, av[f], nsum[f]);
        }
        #pragma unroll
        for (int o = 1; o < 64; o <<= 1) {
            dsum += __shfl_xor(dsum, o, 64);
            #pragma unroll
            for (int f = 0; f < FF; ++f) nsum[f] += __shfl_xor(nsum[f], o, 64);
        }
        if (lane == 0) {
            float inv = dsum != 0.f ? 1.f / dsum : 0.f;
            #pragma unroll
            for (int f = 0; f < FF; ++f) {
                float t = leakyf(nsum[f] * inv + biasg[f], 0.01f);
                t += x0[n * FF + f];
                if (LAYER == 1) t += x1n0[n * FF + f] + x2[n * FF + f];
                h[n * FF + f] = t;
                s1 += t;
                s2 += (double)t * (double)t;
            }
        }
    }
    if (lane == 0) { sh[wid * 2] = s1; sh[wid * 2 + 1] = s2; }
    __syncthreads();
    if (threadIdx.x == 0) {
        atomicAdd(&Sout[0], sh[0] + sh[2] + sh[4] + sh[6]);
        atomicAdd(&Sout[1], sh[1] + sh[3] + sh[5] + sh[7]);
    }
}

// ---------- FFN ----------
template <int LAYER>
__global__ __launch_bounds__(NODE_BLOCK)
void node_ffn(const float* __restrict__ h, const double* __restrict__ Snorm,
              const float* __restrict__ f1W, const float* __restrict__ f1b,
              const float* __restrict__ f2W, const float* __restrict__ f2b,
              const float* __restrict__ x0, const float* __restrict__ x1n0_in,
              const float* __restrict__ x2,
              float* __restrict__ x1n0_out, float* __restrict__ gout,
              double* __restrict__ Sgout,
              const float* __restrict__ head, float* __restrict__ dout) {
    int n = blockIdx.x * blockDim.x + threadIdx.x;
    double s1 = 0.0, s2 = 0.0;
    if (n < NN) {
        float mu, istd;
        norm_params(Snorm, mu, istd);
        float xn[FF];
        #pragma unroll
        for (int f = 0; f < FF; ++f) xn[f] = (h[n * FF + f] - mu) * istd;

        float u[FF], w[FF];
        #pragma unroll
        for (int j = 0; j < FF; ++j) u[j] = f1b[j];
        #pragma unroll
        for (int k = 0; k < FF; ++k) {
            float vk = xn[k];
            #pragma unroll
            for (int j = 0; j < FF; ++j) u[j] = fmaf(vk, f1W[k * FF + j], u[j]);
        }
        #pragma unroll
        for (int j = 0; j < FF; ++j) u[j] = leakyf(u[j], 0.01f);
        #pragma unroll
        for (int j = 0; j < FF; ++j) w[j] = f2b[j];
        #pragma unroll
        for (int k = 0; k < FF; ++k) {
            float vk = u[k];
            #pragma unroll
            for (int j = 0; j < FF; ++j) w[j] = fmaf(vk, f2W[k * FF + j], w[j]);
        }
        #pragma unroll
        for (int f = 0; f < FF; ++f) {
            w[f] += xn[f] + x0[n * FF + f];
            if (LAYER == 1) w[f] += x2[n * FF + f] + x1n0_in[n * FF + f];
        }
        if (LAYER == 0) {
            #pragma unroll
            for (int f = 0; f < FF; ++f) {
                x1n0_out[n * FF + f] = xn[f];
                gout[n * FF + f]     = w[f];
                s1 += w[f];
                s2 += (double)w[f] * (double)w[f];
            }
        } else {
            float o1 = head[6], o2 = head[14];
            #pragma unroll
            for (int f = 0; f < FF; ++f) {
                o1 = fmaf(w[f], head[f], o1);
                o2 = fmaf(w[f], head[8 + f], o2);
            }
            dout[n * 2 + 0] = o1;
            dout[n * 2 + 1] = o2;
        }
    }
    if (LAYER == 0) reduce2_add(s1, s2, Sgout);
}

// ---------- legacy atomic fallback (R0 path) ----------
__global__ __launch_bounds__(NODE_BLOCK)
void zero_accum(float* __restrict__ num, float* __restrict__ denomv) {
    int n = blockIdx.x * blockDim.x + threadIdx.x;
    if (n >= NN) return;
    float4* nm4 = reinterpret_cast<float4*>(num + n * 8);
    nm4[0] = make_float4(0.f, 0.f, 0.f, 0.f);
    nm4[1] = make_float4(0.f, 0.f, 0.f, 0.f);
    denomv[n] = 0.f;
}

__global__ __launch_bounds__(EDGE_BLOCK)
void edge_pass(const int* __restrict__ ei, const float* __restrict__ eattr,
               const float* __restrict__ xl, const float* __restrict__ xr,
               const float* __restrict__ Wef, const float* __restrict__ attf,
               float* __restrict__ num, float* __restrict__ denomv) {
    float we0[FF], we1[FF], at[FF];
    #pragma unroll
    for (int f = 0; f < FF; ++f) { we0[f] = Wef[f]; we1[f] = Wef[FF + f]; at[f] = attf[f]; }
    int idx = blockIdx.x * blockDim.x + threadIdx.x;
    if (idx >= EE) return;
    int s = ei[idx] % NN;
    int d = ei[EE + idx] % NN;
    float2 ea = reinterpret_cast<const float2*>(eattr)[idx];
    const float4* xls = reinterpret_cast<const float4*>(xl + (size_t)s * 8);
    float4 a0 = xls[0], a1 = xls[1];
    const float4* xrd = reinterpret_cast<const float4*>(xr + (size_t)d * 8);
    float4 b0 = xrd[0], b1 = xrd[1];
    float av[FF] = {a0.x, a0.y, a0.z, a0.w, a1.x, a1.y};
    float bv[FF] = {b0.x, b0.y, b0.z, b0.w, b1.x, b1.y};
    float logit = 0.f;
    #pragma unroll
    for (int f = 0; f < FF; ++f) {
        float m = av[f] + bv[f] + fmaf(ea.y, we1[f], ea.x * we0[f]);
        m = m >= 0.f ? m : 0.2f * m;
        logit = fmaf(at[f], m, logit);
    }
    float w = __expf(logit);
    unsafeAtomicAdd(&denomv[d], w);
    float* nd = num + (size_t)d * 8;
    #pragma unroll
    for (int f = 0; f < FF; ++f) unsafeAtomicAdd(&nd[f], w * av[f]);
}

template <int LAYER>
__global__ __launch_bounds__(NODE_BLOCK)
void node_finalize(const float* __restrict__ num, const float* __restrict__ denomv,
                   const float* __restrict__ biasg,
                   const float* __restrict__ x0, const float* __restrict__ x1n0,
                   const float* __restrict__ x2,
                   float* __restrict__ h, double* __restrict__ Sout) {
    int n = blockIdx.x * blockDim.x + threadIdx.x;
    double s1 = 0.0, s2 = 0.0;
    if (n < NN) {
        float dn  = denomv[n];
        float inv = dn != 0.f ? 1.f / dn : 0.f;
        #pragma unroll
        for (int f = 0; f < FF; ++f) {
            float t = leakyf(num[n * 8 + f] * inv + biasg[f], 0.01f);
            t += x0[n * FF + f];
            if (LAYER == 1) t += x1n0[n * FF + f] + x2[n * FF + f];
            h[n * FF + f] = t;
            s1 += t;
            s2 += (double)t * (double)t;
        }
    }
    reduce2_add(s1, s2, Sout);
}

// ---------------------------------------------------------------

extern "C" void kernel_launch(void* const* d_in, const int* in_sizes, int n_in,
                              void* d_out, int out_size, void* d_ws, size_t ws_size,
                              hipStream_t stream) {
    const float* x     = (const float*)d_in[0];
    const float* eattr = (const float*)d_in[1];
    const float* Wl    = (const float*)d_in[2];
    const float* bl    = (const float*)d_in[3];
    const float* Wr    = (const float*)d_in[4];
    const float* br    = (const float*)d_in[5];
    const float* We    = (const float*)d_in[6];
    const float* att   = (const float*)d_in[7];
    const float* biasg = (const float*)d_in[8];
    const float* ff1W  = (const float*)d_in[9];
    const float* ff1b  = (const float*)d_in[10];
    const float* ff2W  = (const float*)d_in[11];
    const float* ff2b  = (const float*)d_in[12];
    const float* Wresh = (const float*)d_in[13];
    const float* bresh = (const float*)d_in[14];
    const float* W1    = (const float*)d_in[15];
    const float* b1    = (const float*)d_in[16];
    const float* W2    = (const float*)d_in[17];
    const float* b2    = (const float*)d_in[18];
    const int*   ei    = (const int*)d_in[19];
    float* out = (float*)d_out;

    char* p = (char*)d_ws;
    auto alloc = [&](size_t bytes) -> char* {
        char* r = p;
        p += (bytes + 255) & ~size_t(255);
        return r;
    };

    double*   S     = (double*)alloc(8 * sizeof(double));
    float*    head  = (float*)alloc(16 * sizeof(float));
    float*    xl    = (float*)alloc((size_t)NN * 8 * sizeof(float));
    float*    xr    = (float*)alloc((size_t)NN * 8 * sizeof(float));
    float*    h     = (float*)alloc((size_t)NN * FF * sizeof(float));
    float*    x1n0  = (float*)alloc((size_t)NN * FF * sizeof(float));
    float*    x2    = (float*)alloc((size_t)NN * FF * sizeof(float));
    float*    g     = (float*)alloc((size_t)NN * FF * sizeof(float));
    // CSR region
    unsigned* counts = (unsigned*)alloc((size_t)NN * sizeof(unsigned));
    int*      offs   = (int*)alloc((size_t)(NN + 1) * sizeof(int));
    unsigned* rank   = (unsigned*)alloc((size_t)EE * sizeof(unsigned));
    int*      srcs   = (int*)alloc((size_t)EE * sizeof(int));
    float*    eas    = (float*)alloc((size_t)EE * 2 * sizeof(float));
    size_t need_fast = (size_t)(p - (char*)d_ws);

    head_prep<<<1, 64, 0, stream>>>(Wresh, bresh, W1, b1, W2, b2, head, S);

    if (ws_size >= need_fast) {
        // ---- CSR build (once; graph is shared by both layers) ----
        zero_counts<<<(NN + 255) / 256, 256, 0, stream>>>(counts);
        count_edges<<<EDGE_GRID, EDGE_BLOCK, 0, stream>>>(ei, counts, rank);
        scan_counts<<<1, 1024, 0, stream>>>(counts, offs);
        scatter_edges<<<EDGE_GRID, EDGE_BLOCK, 0, stream>>>(ei, rank, eattr, offs, srcs, eas);

        // ---- layer 0 ----
        node_transform<0><<<NODE_GRID, NODE_BLOCK, 0, stream>>>(
            x, nullptr, Wl, bl, Wr, br, xl, xr, nullptr);
        gat_gather<0><<<NN / 4, 256, 0, stream>>>(
            offs, srcs, eas, xl, xr, We, att, biasg, x, nullptr, nullptr, h, S + 0);
        node_ffn<0><<<NODE_GRID, NODE_BLOCK, 0, stream>>>(
            h, S + 0, ff1W, ff1b, ff2W, ff2b, x, nullptr, nullptr,
            x1n0, g, S + 2, nullptr, nullptr);

        // ---- layer 1 ----
        node_transform<1><<<NODE_GRID, NODE_BLOCK, 0, stream>>>(
            g, S + 2, Wl + 36, bl + 6, Wr + 36, br + 6, xl, xr, x2);
        gat_gather<1><<<NN / 4, 256, 0, stream>>>(
            offs, srcs, eas, xl, xr, We + 12, att + 6, biasg + 6, x, x1n0, x2, h, S + 4);
        node_ffn<1><<<NODE_GRID, NODE_BLOCK, 0, stream>>>(
            h, S + 4, ff1W + 36, ff1b + 6, ff2W + 36, ff2b + 6, x, x1n0, x2,
            nullptr, nullptr, nullptr, head, out);
    } else {
        // ---- legacy atomic path (R0) ----
        char* q = (char*)d_ws + (((8 * sizeof(double) + 16 * sizeof(float)) + 255) & ~size_t(255));
        auto alloc2 = [&](size_t bytes) -> char* {
            char* r = q;
            q += (bytes + 255) & ~size_t(255);
            return r;
        };
        float* xl2  = (float*)alloc2((size_t)NN * 8 * sizeof(float));
        float* xr2  = (float*)alloc2((size_t)NN * 8 * sizeof(float));
        float* num  = (float*)alloc2((size_t)NN * 8 * sizeof(float));
        float* dnm  = (float*)alloc2((size_t)NN * sizeof(float));
        float* h2   = (float*)alloc2((size_t)NN * FF * sizeof(float));
        float* x1b  = (float*)alloc2((size_t)NN * FF * sizeof(float));
        float* x2b  = (float*)alloc2((size_t)NN * FF * sizeof(float));
        float* gb   = (float*)alloc2((size_t)NN * FF * sizeof(float));

        node_transform<0><<<NODE_GRID, NODE_BLOCK, 0, stream>>>(
            x, nullptr, Wl, bl, Wr, br, xl2, xr2, nullptr);
        zero_accum<<<NODE_GRID, NODE_BLOCK, 0, stream>>>(num, dnm);
        edge_pass<<<EDGE_GRID, EDGE_BLOCK, 0, stream>>>(ei, eattr, xl2, xr2, We, att, num, dnm);
        node_finalize<0><<<NODE_GRID, NODE_BLOCK, 0, stream>>>(
            num, dnm, biasg, x, nullptr, nullptr, h2, S + 0);
        node_ffn<0><<<NODE_GRID, NODE_BLOCK, 0, stream>>>(
            h2, S + 0, ff1W, ff1b, ff2W, ff2b, x, nullptr, nullptr,
            x1b, gb, S + 2, nullptr, nullptr);

        node_transform<1><<<NODE_GRID, NODE_BLOCK, 0, stream>>>(
            gb, S + 2, Wl + 36, bl + 6, Wr + 36, br + 6, xl2, xr2, x2b);
        zero_accum<<<NODE_GRID, NODE_BLOCK, 0, stream>>>(num, dnm);
        edge_pass<<<EDGE_GRID, EDGE_BLOCK, 0, stream>>>(ei, eattr, xl2, xr2, We + 12, att + 6, num, dnm);
        node_finalize<1><<<NODE_GRID, NODE_BLOCK, 0, stream>>>(
            num, dnm, biasg + 6, x, x1b, x2b, h2, S + 4);
        node_ffn<1><<<NODE_GRID, NODE_BLOCK, 0, stream>>>(
            h2, S + 4, ff1W + 36, ff1b + 6, ff2W + 36, ff2b + 6, x, x1b, x2b,
            nullptr, nullptr, nullptr, head, out);
    }
}